// Round 9
// baseline (631.994 us; speedup 1.0000x reference)
//
#include <hip/hip_runtime.h>
#include <hip/hip_bf16.h>
#include <cstdint>
#include <cstddef>

typedef __hip_bfloat16 bf16;
using f32x4  = __attribute__((ext_vector_type(4))) float;
using bf16x8 = __attribute__((ext_vector_type(8))) short;

#define DEVI __device__ __forceinline__

DEVI int reg3(int u) { return (u < 49) ? 0 : ((u < 53) ? 1 : 2); }

DEVI unsigned short f2bu(float v) {
  bf16 b = __float2bfloat16(v);
  return *reinterpret_cast<unsigned short*>(&b);
}

// exp-based tanh GELU (max |err| vs exact-erf GELU ~1.5e-3, NaN-free at any x)
DEVI float gelu_f(float v) {
  const float y = 0.7978845608028654f * (v + 0.044715f * v * v * v);
  const float e = __expf(2.0f * y);
  const float th = 1.0f - 2.0f / (e + 1.0f);     // tanh(y)
  return 0.5f * v * (1.0f + th);
}

// async global->LDS, 16B per lane; dest = ldsbase + lane*16 (linear, wave-uniform base)
DEVI void gload_lds16(const void* g, void* l) {
  __builtin_amdgcn_global_load_lds(
      (const __attribute__((address_space(1))) unsigned int*)g,
      (__attribute__((address_space(3))) unsigned int*)l, 16, 0, 0);
}

// ---------- fp32 -> bf16 weight conversion ----------
__global__ __launch_bounds__(256) void cvt_kernel(const float* __restrict__ src,
                                                  bf16* __restrict__ dst, int n)
{
  const int i = blockIdx.x * 256 + threadIdx.x;
  if (i < n) dst[i] = __float2bfloat16(src[i]);
}

// ---------- LayerNorm over C=192 (fp32 in, bf16 out), shift+window gather (attn path) ----------
template<bool PERM>
__global__ __launch_bounds__(256) void ln_kernel(const float* __restrict__ x,
                                                 const float* __restrict__ gw,
                                                 const float* __restrict__ bw,
                                                 bf16* __restrict__ out,
                                                 int grow0)
{
  const int lane = threadIdx.x & 63;
  const int ridx = blockIdx.x * 4 + (threadIdx.x >> 6);
  size_t src;
  if (PERM) {
    const int g   = grow0 + ridx;
    const int wid = g / 49;
    const int nn  = g - wid * 49;
    const int b_  = wid >> 6, wim = wid & 63;
    const int wy  = wim >> 3, wx = wim & 7;
    const int ny  = nn / 7,  nx = nn - (nn / 7) * 7;
    int i = wy * 7 + ny + 3; if (i >= 56) i -= 56;   // shifted coord u reads x[(u+3)%56]
    int j = wx * 7 + nx + 3; if (j >= 56) j -= 56;
    src = (size_t)(b_ * 3136 + i * 56 + j);
  } else {
    src = (size_t)ridx;
  }
  const float* xr = x + src * 192;
  float v0 = xr[lane];
  float v1 = xr[lane + 64];
  float v2 = xr[lane + 128];
  float s = v0 + v1 + v2;
#pragma unroll
  for (int off = 32; off > 0; off >>= 1) s += __shfl_xor(s, off);
  const float mu = s * (1.0f / 192.0f);
  const float d0 = v0 - mu, d1 = v1 - mu, d2 = v2 - mu;
  float vs = d0 * d0 + d1 * d1 + d2 * d2;
#pragma unroll
  for (int off = 32; off > 0; off >>= 1) vs += __shfl_xor(vs, off);
  const float rstd = rsqrtf(vs * (1.0f / 192.0f) + 1e-5f);
  bf16* orow = out + (size_t)ridx * 192;
  orow[lane]       = __float2bfloat16(d0 * rstd * gw[lane]       + bw[lane]);
  orow[lane + 64]  = __float2bfloat16(d1 * rstd * gw[lane + 64]  + bw[lane + 64]);
  orow[lane + 128] = __float2bfloat16(d2 * rstd * gw[lane + 128] + bw[lane + 128]);
}

// ---------- GEMM (attn path: QKV / proj) — unchanged from R8 ----------
template<int MODE>
__global__ __launch_bounds__(256) void gemm_kernel(const bf16* __restrict__ A,
                                                   const bf16* __restrict__ Bt,
                                                   const float* __restrict__ bias,
                                                   const float* __restrict__ resid,
                                                   void* __restrict__ outv,
                                                   int N, int K, int grow0)
{
  __shared__ short lds[2][128 * 64 + 192 * 64];  // 2 x (A[128][64] + B[192][64]) = 80 KiB
  const int tid  = threadIdx.x;
  const int lane = tid & 63;
  const int w    = tid >> 6;
  const int wm   = (w >> 1) * 64;
  const int wn   = (w & 1) * 96;
  const int m0   = blockIdx.y * 128;
  const int n0   = blockIdx.x * 192;
  const int lrow = lane >> 3;
  const int lseg = lane & 7;
  const int ksw  = (lseg * 8) ^ (lrow << 3);   // pre-swizzled source k (elements)

  f32x4 acc[4][6];
#pragma unroll
  for (int i = 0; i < 4; i++)
#pragma unroll
    for (int j = 0; j < 6; j++) acc[i][j] = (f32x4){0.f, 0.f, 0.f, 0.f};

  const int nk = K >> 6;

  auto issue = [&](int buf, int kt) {
    const int k0 = kt << 6;
    short* LA = &lds[buf][0];
    short* LB = &lds[buf][128 * 64];
#pragma unroll
    for (int i = 0; i < 4; i++) {
      const int chunk = w * 4 + i;
      gload_lds16(A + (size_t)(m0 + chunk * 8 + lrow) * K + (k0 + ksw), LA + chunk * 512);
    }
#pragma unroll
    for (int i = 0; i < 6; i++) {
      const int chunk = w * 6 + i;
      gload_lds16(Bt + (size_t)(n0 + chunk * 8 + lrow) * K + (k0 + ksw), LB + chunk * 512);
    }
  };

  issue(0, 0);
  __syncthreads();

  for (int kt = 0; kt < nk; kt++) {
    const int buf = kt & 1;
    if (kt + 1 < nk) issue(buf ^ 1, kt + 1);
    const char* LA = (const char*)&lds[buf][0];
    const char* LB = (const char*)&lds[buf][128 * 64];
#pragma unroll
    for (int kk = 0; kk < 2; kk++) {
      bf16x8 af[4], bg[6];
#pragma unroll
      for (int mf = 0; mf < 4; mf++) {
        const int row = wm + mf * 16 + (lane & 15);
        const int kb  = (kk * 64 + ((lane >> 4) << 4)) ^ ((row & 7) << 4);
        af[mf] = *(const bf16x8*)(LA + row * 128 + kb);
      }
#pragma unroll
      for (int nf = 0; nf < 6; nf++) {
        const int row = wn + nf * 16 + (lane & 15);
        const int kb  = (kk * 64 + ((lane >> 4) << 4)) ^ ((row & 7) << 4);
        bg[nf] = *(const bf16x8*)(LB + row * 128 + kb);
      }
#pragma unroll
      for (int mf = 0; mf < 4; mf++)
#pragma unroll
        for (int nf = 0; nf < 6; nf++)
          acc[mf][nf] = __builtin_amdgcn_mfma_f32_16x16x32_bf16(af[mf], bg[nf], acc[mf][nf], 0, 0, 0);
    }
    __syncthreads();
  }

  float bv[6];
  int ncol[6];
#pragma unroll
  for (int nf = 0; nf < 6; nf++) {
    ncol[nf] = n0 + wn + nf * 16 + (lane & 15);
    bv[nf]   = bias[ncol[nf]];
  }
#pragma unroll
  for (int mf = 0; mf < 4; mf++) {
#pragma unroll
    for (int r = 0; r < 4; r++) {
      const int m = m0 + wm + mf * 16 + ((lane >> 4) << 2) + r;
      if constexpr (MODE == 1) {
        const int gm  = grow0 + m;
        const int wid = gm / 49;
        const int nn  = gm - wid * 49;
        const int b_  = wid >> 6, wim = wid & 63;
        const int wy  = wim >> 3, wx = wim & 7;
        const int ny  = nn / 7, nx = nn - (nn / 7) * 7;
        int i = wy * 7 + ny + 3; if (i >= 56) i -= 56;
        int j = wx * 7 + nx + 3; if (j >= 56) j -= 56;
        const size_t t = (size_t)(b_ * 3136 + i * 56 + j) * 192;
        float* O = (float*)outv;
#pragma unroll
        for (int nf = 0; nf < 6; nf++)
          O[t + ncol[nf]] = acc[mf][nf][r] + bv[nf] + resid[t + ncol[nf]];
      } else {
        bf16* O = (bf16*)outv + (size_t)m * N;
#pragma unroll
        for (int nf = 0; nf < 6; nf++)
          O[ncol[nf]] = __float2bfloat16(acc[mf][nf][r] + bv[nf]);
      }
    }
  }
}

// ---------- fused MLP: LN2 + fc1 + GELU + fc2 + residual, one block = 32 rows ----------
// a0[32][192], a1[32][768] bf16 in LDS, XOR-swizzled (byte ^ (row&7)<<4, GEMM-proven).
// B-operands (wfc1/wfc2, L2-resident) load direct global->VGPR: wave's 4 k-offset lane
// groups cover full 64B lines. 512 thr / 8 waves (2m x 4n); LDS 60 KB -> 2 blocks/CU.
__global__ __launch_bounds__(512, 4) void mlp_kernel(const float* __restrict__ x,
                                                     const float* __restrict__ g2,
                                                     const float* __restrict__ b2,
                                                     const bf16* __restrict__ w1,
                                                     const float* __restrict__ b1f,
                                                     const bf16* __restrict__ w2,
                                                     const float* __restrict__ b2f,
                                                     float* __restrict__ out)
{
  __shared__ char a0[32 * 384];    // [32][192] bf16 swizzled, 12 KiB
  __shared__ char a1[32 * 1536];   // [32][768] bf16 swizzled, 48 KiB
  const int tid  = threadIdx.x;
  const int lane = tid & 63;
  const int w    = tid >> 6;
  const int m0   = blockIdx.x * 32;

  // ---- phase 0: LN2 on 32 rows (wave w handles rows w*4 .. w*4+3) ----
#pragma unroll
  for (int i = 0; i < 4; i++) {
    const int r = w * 4 + i;
    const float* xr = x + (size_t)(m0 + r) * 192;
    float v0 = xr[lane], v1 = xr[lane + 64], v2 = xr[lane + 128];
    float s = v0 + v1 + v2;
#pragma unroll
    for (int off = 32; off > 0; off >>= 1) s += __shfl_xor(s, off);
    const float mu = s * (1.0f / 192.0f);
    const float d0 = v0 - mu, d1 = v1 - mu, d2 = v2 - mu;
    float vs = d0 * d0 + d1 * d1 + d2 * d2;
#pragma unroll
    for (int off = 32; off > 0; off >>= 1) vs += __shfl_xor(vs, off);
    const float rstd = rsqrtf(vs * (1.0f / 192.0f) + 1e-5f);
    const int rx = (r & 7) << 4;
    *(unsigned short*)(a0 + r * 384 + ((2 * lane) ^ rx))         = f2bu(d0 * rstd * g2[lane]       + b2[lane]);
    *(unsigned short*)(a0 + r * 384 + ((2 * (lane + 64)) ^ rx))  = f2bu(d1 * rstd * g2[lane + 64]  + b2[lane + 64]);
    *(unsigned short*)(a0 + r * 384 + ((2 * (lane + 128)) ^ rx)) = f2bu(d2 * rstd * g2[lane + 128] + b2[lane + 128]);
  }
  __syncthreads();

  const int wm  = (w >> 2) * 16;      // 0 | 16
  const int wn1 = (w & 3) * 192;      // fc1 col group
  const int ar  = wm + (lane & 15);   // A-fragment row (phases 1 & 2)
  const int arx = (ar & 7) << 4;
  const int kq  = (lane >> 4);        // k-quarter 0..3

  // ---- phase 1: a1 = gelu(a0 @ w1^T + b1) ----
  f32x4 acc1[12];
#pragma unroll
  for (int j = 0; j < 12; j++) acc1[j] = (f32x4){0.f, 0.f, 0.f, 0.f};
  for (int kk = 0; kk < 6; kk++) {
    const bf16x8 af = *(const bf16x8*)(a0 + ar * 384 + ((kk * 64 + (kq << 4)) ^ arx));
    const int kel = kk * 32 + (kq << 3);
#pragma unroll
    for (int h = 0; h < 2; h++) {           // two batches of 6 to bound VGPR peak
      bf16x8 bf_[6];
#pragma unroll
      for (int nf = 0; nf < 6; nf++)
        bf_[nf] = *(const bf16x8*)(w1 + (size_t)(wn1 + (h * 6 + nf) * 16 + (lane & 15)) * 192 + kel);
#pragma unroll
      for (int nf = 0; nf < 6; nf++)
        acc1[h * 6 + nf] = __builtin_amdgcn_mfma_f32_16x16x32_bf16(af, bf_[nf], acc1[h * 6 + nf], 0, 0, 0);
    }
  }
  {
    float bv[12];
#pragma unroll
    for (int nf = 0; nf < 12; nf++) bv[nf] = b1f[wn1 + nf * 16 + (lane & 15)];
#pragma unroll
    for (int nf = 0; nf < 12; nf++)
#pragma unroll
      for (int r = 0; r < 4; r++) {
        const int row = wm + (kq << 2) + r;
        const int col = wn1 + nf * 16 + (lane & 15);
        *(unsigned short*)(a1 + row * 1536 + ((2 * col) ^ ((row & 7) << 4)))
            = f2bu(gelu_f(acc1[nf][r] + bv[nf]));
      }
  }
  __syncthreads();

  // ---- phase 2: out += a1 @ w2^T + b2 ----
  const int wn2 = (w & 3) * 48;
  f32x4 acc2[3];
#pragma unroll
  for (int j = 0; j < 3; j++) acc2[j] = (f32x4){0.f, 0.f, 0.f, 0.f};
  for (int kk = 0; kk < 24; kk++) {
    const bf16x8 af = *(const bf16x8*)(a1 + ar * 1536 + ((kk * 64 + (kq << 4)) ^ arx));
    const int kel = kk * 32 + (kq << 3);
    bf16x8 bf_[3];
#pragma unroll
    for (int nf = 0; nf < 3; nf++)
      bf_[nf] = *(const bf16x8*)(w2 + (size_t)(wn2 + nf * 16 + (lane & 15)) * 768 + kel);
#pragma unroll
    for (int nf = 0; nf < 3; nf++)
      acc2[nf] = __builtin_amdgcn_mfma_f32_16x16x32_bf16(af, bf_[nf], acc2[nf], 0, 0, 0);
  }
  {
    float bv[3];
#pragma unroll
    for (int nf = 0; nf < 3; nf++) bv[nf] = b2f[wn2 + nf * 16 + (lane & 15)];
#pragma unroll
    for (int nf = 0; nf < 3; nf++)
#pragma unroll
      for (int r = 0; r < 4; r++) {
        const int row = wm + (kq << 2) + r;
        const size_t o = (size_t)(m0 + row) * 192 + wn2 + nf * 16 + (lane & 15);
        out[o] = acc2[nf][r] + bv[nf] + out[o];
      }
  }
}

// ---------- MFMA windowed attention (unchanged from R7/R8) ----------
__global__ __launch_bounds__(64) void attn_kernel(const bf16* __restrict__ qkv,
                                                  const float* __restrict__ rpb,
                                                  bf16* __restrict__ aout)
{
  __shared__ unsigned short Vt[32 * 64];
  __shared__ unsigned short Pl[64 * 64];
  __shared__ float Bl[169];
  const int lane = threadIdx.x;
  const int wid  = blockIdx.x;
  const int h    = blockIdx.y;
  const unsigned short* qkvu = (const unsigned short*)qkv;
  const size_t base = (size_t)wid * 49 * 576 + h * 32;

#pragma unroll
  for (int i = 0; i < 3; i++) {
    const int idx = lane + 64 * i;
    if (idx < 169) Bl[idx] = rpb[idx * 6 + h];
  }
#pragma unroll
  for (int i = 0; i < 8; i++)
    ((unsigned long long*)Vt)[lane + 64 * i] = 0ull;

#pragma unroll
  for (int it = 0; it < 7; it++) {
    const int idx = lane + 64 * it;
    if (idx < 392) {
      const int n  = idx >> 3;
      const int d0 = (idx & 7) * 4;
      ushort4 v = *(const ushort4*)(qkvu + base + (size_t)n * 576 + 384 + d0);
      Vt[(d0 + 0) * 64 + (n ^ (((d0 + 0) & 7) << 3))] = v.x;
      Vt[(d0 + 1) * 64 + (n ^ (((d0 + 1) & 7) << 3))] = v.y;
      Vt[(d0 + 2) * 64 + (n ^ (((d0 + 2) & 7) << 3))] = v.z;
      Vt[(d0 + 3) * 64 + (n ^ (((d0 + 3) & 7) << 3))] = v.w;
    }
  }

  bf16x8 qf[4], kf[4];
#pragma unroll
  for (int t = 0; t < 4; t++) {
    int rq = (lane & 15) + t * 16; if (rq > 48) rq = 48;
    qf[t] = *(const bf16x8*)(qkvu + base + (size_t)rq * 576 + ((lane >> 4) * 8));
    kf[t] = *(const bf16x8*)(qkvu + base + (size_t)rq * 576 + 192 + ((lane >> 4) * 8));
  }

  f32x4 s[4][4];
#pragma unroll
  for (int mt = 0; mt < 4; mt++)
#pragma unroll
    for (int nt = 0; nt < 4; nt++)
      s[mt][nt] = __builtin_amdgcn_mfma_f32_16x16x32_bf16(qf[mt], kf[nt],
                    (f32x4){0.f, 0.f, 0.f, 0.f}, 0, 0, 0);

  const int wim = wid & 63;
  const int wy = wim >> 3, wx = wim & 7;
  int labn[4], ch[4], cw[4];
  bool cval[4];
#pragma unroll
  for (int nt = 0; nt < 4; nt++) {
    const int C = (lane & 15) + nt * 16;
    cval[nt] = (C < 49);
    const int cc = cval[nt] ? C : 48;
    ch[nt] = cc / 7; cw[nt] = cc - ch[nt] * 7;
    labn[nt] = reg3(wy * 7 + ch[nt]) * 3 + reg3(wx * 7 + cw[nt]);
  }

#pragma unroll
  for (int mt = 0; mt < 4; mt++) {
    f32x4 rm, sm, inv;
#pragma unroll
    for (int r = 0; r < 4; r++) {
      int R = mt * 16 + ((lane >> 4) << 2) + r; if (R > 48) R = 48;
      const int mh = R / 7, mw = R - (R / 7) * 7;
      const int labm = reg3(wy * 7 + mh) * 3 + reg3(wx * 7 + mw);
#pragma unroll
      for (int nt = 0; nt < 4; nt++) {
        float sv = s[mt][nt][r] * 0.1767766953f
                 + Bl[(mh - ch[nt] + 6) * 13 + (mw - cw[nt] + 6)];
        if (labn[nt] != labm) sv -= 100.f;
        if (!cval[nt]) sv = -3e38f;
        s[mt][nt][r] = sv;
      }
      rm[r] = fmaxf(fmaxf(s[mt][0][r], s[mt][1][r]), fmaxf(s[mt][2][r], s[mt][3][r]));
    }
#pragma unroll
    for (int mk = 1; mk < 16; mk <<= 1)
#pragma unroll
      for (int r = 0; r < 4; r++) rm[r] = fmaxf(rm[r], __shfl_xor(rm[r], mk));
#pragma unroll
    for (int r = 0; r < 4; r++) {
      float acc = 0.f;
#pragma unroll
      for (int nt = 0; nt < 4; nt++) {
        const float p = __expf(s[mt][nt][r] - rm[r]);
        s[mt][nt][r] = p;
        acc += p;
      }
      sm[r] = acc;
    }
#pragma unroll
    for (int mk = 1; mk < 16; mk <<= 1)
#pragma unroll
      for (int r = 0; r < 4; r++) sm[r] += __shfl_xor(sm[r], mk);
#pragma unroll
    for (int r = 0; r < 4; r++) inv[r] = 1.0f / sm[r];
#pragma unroll
    for (int nt = 0; nt < 4; nt++)
#pragma unroll
      for (int r = 0; r < 4; r++) {
        const int R = mt * 16 + ((lane >> 4) << 2) + r;
        const int C = (lane & 15) + nt * 16;
        Pl[R * 64 + (C ^ ((R & 7) << 3))] = f2bu(s[mt][nt][r] * inv[r]);
      }
  }

  f32x4 o[4][2];
#pragma unroll
  for (int mt = 0; mt < 4; mt++)
#pragma unroll
    for (int n2 = 0; n2 < 2; n2++) o[mt][n2] = (f32x4){0.f, 0.f, 0.f, 0.f};
#pragma unroll
  for (int kk = 0; kk < 2; kk++) {
    const int kb = kk * 64 + ((lane >> 4) << 4);
    bf16x8 vb[2];
#pragma unroll
    for (int n2 = 0; n2 < 2; n2++) {
      const int d = (lane & 15) + n2 * 16;
      vb[n2] = *(const bf16x8*)((const char*)Vt + d * 128 + (kb ^ ((d & 7) << 4)));
    }
#pragma unroll
    for (int mt = 0; mt < 4; mt++) {
      const int R = (lane & 15) + mt * 16;
      const bf16x8 pa = *(const bf16x8*)((const char*)Pl + R * 128 + (kb ^ ((R & 7) << 4)));
#pragma unroll
      for (int n2 = 0; n2 < 2; n2++)
        o[mt][n2] = __builtin_amdgcn_mfma_f32_16x16x32_bf16(pa, vb[n2], o[mt][n2], 0, 0, 0);
    }
  }

#pragma unroll
  for (int mt = 0; mt < 4; mt++)
#pragma unroll
    for (int r = 0; r < 4; r++) {
      const int R = mt * 16 + ((lane >> 4) << 2) + r;
      if (R < 49) {
        bf16* orow = aout + (size_t)(wid * 49 + R) * 192 + h * 32;
#pragma unroll
        for (int n2 = 0; n2 < 2; n2++)
          orow[n2 * 16 + (lane & 15)] = __float2bfloat16(o[mt][n2][r]);
      }
    }
}

extern "C" void kernel_launch(void* const* d_in, const int* in_sizes, int n_in,
                              void* d_out, int out_size, void* d_ws, size_t ws_size,
                              hipStream_t stream)
{
  (void)in_sizes; (void)n_in; (void)out_size;
  const float* x     = (const float*)d_in[0];
  const float* ln1g  = (const float*)d_in[1];
  const float* ln1b  = (const float*)d_in[2];
  const float* qkvw  = (const float*)d_in[3];
  const float* qkvb  = (const float*)d_in[4];
  const float* projw = (const float*)d_in[5];
  const float* projb = (const float*)d_in[6];
  const float* rpb   = (const float*)d_in[7];
  const float* ln2g  = (const float*)d_in[8];
  const float* ln2b  = (const float*)d_in[9];
  const float* fc1w  = (const float*)d_in[10];
  const float* fc1b  = (const float*)d_in[11];
  const float* fc2w  = (const float*)d_in[12];
  const float* fc2b  = (const float*)d_in[13];
  float* out = (float*)d_out;
  char* ws   = (char*)d_ws;

  // ---- bf16 weight copies at head of ws (884736 B total) ----
  bf16* wqkv = (bf16*)(ws);              // 110592 el
  bf16* wproj = (bf16*)(ws + 221184);    //  36864 el
  bf16* wfc1 = (bf16*)(ws + 294912);     // 147456 el
  bf16* wfc2 = (bf16*)(ws + 589824);     // 147456 el
  cvt_kernel<<<dim3(432), dim3(256), 0, stream>>>(qkvw, wqkv, 110592);
  cvt_kernel<<<dim3(144), dim3(256), 0, stream>>>(projw, wproj, 36864);
  cvt_kernel<<<dim3(576), dim3(256), 0, stream>>>(fc1w, wfc1, 147456);
  cvt_kernel<<<dim3(576), dim3(256), 0, stream>>>(fc2w, wfc2, 147456);

  char* cws = ws + 884736;
  const size_t avail = (ws_size > 884736ull) ? ws_size - 884736ull : 0;

  // ---- attention pipeline, chunked over batch (permutes are batch-local) ----
  int Bc = 32;
  while (Bc > 2 && (size_t)Bc * 4816896ull > avail) Bc >>= 1;
  const int nb = 32 / Bc;
  bf16* qkv_c  = (bf16*)cws;
  bf16* hwin_c = (bf16*)(cws + (size_t)Bc * 3612672ull);

  for (int c = 0; c < nb; c++) {
    const int R0 = c * Bc * 3136;       // global window-row offset
    const int Mc = Bc * 3136;
    ln_kernel<true><<<dim3(Mc / 4), dim3(256), 0, stream>>>(x, ln1g, ln1b, hwin_c, R0);
    gemm_kernel<0><<<dim3(3, Mc / 128), dim3(256), 0, stream>>>(hwin_c, wqkv, qkvb, nullptr, qkv_c, 576, 192, 0);
    attn_kernel<<<dim3(Bc * 64, 6), dim3(64), 0, stream>>>(qkv_c, rpb, hwin_c);
    gemm_kernel<1><<<dim3(1, Mc / 128), dim3(256), 0, stream>>>(hwin_c, wproj, projb, x, out, 192, 192, R0);
  }

  // ---- fused MLP: LN2 + fc1 + GELU + fc2 + residual ----
  mlp_kernel<<<dim3(3136), dim3(512), 0, stream>>>(out, ln2g, ln2b, wfc1, fc1b, wfc2, fc2b, out);
}

// Round 10
// 376.658 us; speedup vs baseline: 1.6779x; 1.6779x over previous
//
#include <hip/hip_runtime.h>
#include <hip/hip_bf16.h>
#include <cstdint>
#include <cstddef>

typedef __hip_bfloat16 bf16;
using f32x4  = __attribute__((ext_vector_type(4))) float;
using bf16x8 = __attribute__((ext_vector_type(8))) short;

#define DEVI __device__ __forceinline__

DEVI int reg3(int u) { return (u < 49) ? 0 : ((u < 53) ? 1 : 2); }

DEVI unsigned short f2bu(float v) {
  bf16 b = __float2bfloat16(v);
  return *reinterpret_cast<unsigned short*>(&b);
}

// exp-based tanh GELU (max |err| vs exact-erf GELU ~1.5e-3, NaN-free at any x)
DEVI float gelu_f(float v) {
  const float y = 0.7978845608028654f * (v + 0.044715f * v * v * v);
  const float e = __expf(2.0f * y);
  const float th = 1.0f - 2.0f / (e + 1.0f);     // tanh(y)
  return 0.5f * v * (1.0f + th);
}

// async global->LDS, 16B per lane; dest = ldsbase + lane*16 (linear, wave-uniform base)
DEVI void gload_lds16(const void* g, void* l) {
  __builtin_amdgcn_global_load_lds(
      (const __attribute__((address_space(1))) unsigned int*)g,
      (__attribute__((address_space(3))) unsigned int*)l, 16, 0, 0);
}

// ---------- fp32 -> bf16 weight conversion (plain layout, attn-path weights) ----------
__global__ __launch_bounds__(256) void cvt_kernel(const float* __restrict__ src,
                                                  bf16* __restrict__ dst, int n)
{
  const int i = blockIdx.x * 256 + threadIdx.x;
  if (i < n) dst[i] = __float2bfloat16(src[i]);
}

// ---------- fp32 -> bf16 fragment-native transpose for MLP weights ----------
// dst flat idx i: e=i&7, l=(i>>3)&63, blk=i>>9; kk=blk%KT, nf=blk/KT (KT = K/32).
// Fragment block (nf,kk) = 64 lanes x 16B contiguous; lane l holds row nf*16+(l&15),
// k = kk*32 + (l>>4)*8 + e  -> B-fragment loads become lane*16B coalesced streams.
__global__ __launch_bounds__(256) void cvtT_kernel(const float* __restrict__ src,
                                                   bf16* __restrict__ dst, int K, int KT, int n)
{
  const int i = blockIdx.x * 256 + threadIdx.x;
  if (i >= n) return;
  const int e   = i & 7;
  const int l   = (i >> 3) & 63;
  const int blk = i >> 9;
  const int kk  = blk % KT;
  const int nf  = blk / KT;
  dst[i] = __float2bfloat16(src[(size_t)(nf * 16 + (l & 15)) * K + kk * 32 + (l >> 4) * 8 + e]);
}

// ---------- LayerNorm over C=192 (fp32 in, bf16 out), shift+window gather (attn path) ----------
template<bool PERM>
__global__ __launch_bounds__(256) void ln_kernel(const float* __restrict__ x,
                                                 const float* __restrict__ gw,
                                                 const float* __restrict__ bw,
                                                 bf16* __restrict__ out,
                                                 int grow0)
{
  const int lane = threadIdx.x & 63;
  const int ridx = blockIdx.x * 4 + (threadIdx.x >> 6);
  size_t src;
  if (PERM) {
    const int g   = grow0 + ridx;
    const int wid = g / 49;
    const int nn  = g - wid * 49;
    const int b_  = wid >> 6, wim = wid & 63;
    const int wy  = wim >> 3, wx = wim & 7;
    const int ny  = nn / 7,  nx = nn - (nn / 7) * 7;
    int i = wy * 7 + ny + 3; if (i >= 56) i -= 56;   // shifted coord u reads x[(u+3)%56]
    int j = wx * 7 + nx + 3; if (j >= 56) j -= 56;
    src = (size_t)(b_ * 3136 + i * 56 + j);
  } else {
    src = (size_t)ridx;
  }
  const float* xr = x + src * 192;
  float v0 = xr[lane];
  float v1 = xr[lane + 64];
  float v2 = xr[lane + 128];
  float s = v0 + v1 + v2;
#pragma unroll
  for (int off = 32; off > 0; off >>= 1) s += __shfl_xor(s, off);
  const float mu = s * (1.0f / 192.0f);
  const float d0 = v0 - mu, d1 = v1 - mu, d2 = v2 - mu;
  float vs = d0 * d0 + d1 * d1 + d2 * d2;
#pragma unroll
  for (int off = 32; off > 0; off >>= 1) vs += __shfl_xor(vs, off);
  const float rstd = rsqrtf(vs * (1.0f / 192.0f) + 1e-5f);
  bf16* orow = out + (size_t)ridx * 192;
  orow[lane]       = __float2bfloat16(d0 * rstd * gw[lane]       + bw[lane]);
  orow[lane + 64]  = __float2bfloat16(d1 * rstd * gw[lane + 64]  + bw[lane + 64]);
  orow[lane + 128] = __float2bfloat16(d2 * rstd * gw[lane + 128] + bw[lane + 128]);
}

// ---------- GEMM (attn path: QKV / proj) — unchanged from R8 ----------
template<int MODE>
__global__ __launch_bounds__(256) void gemm_kernel(const bf16* __restrict__ A,
                                                   const bf16* __restrict__ Bt,
                                                   const float* __restrict__ bias,
                                                   const float* __restrict__ resid,
                                                   void* __restrict__ outv,
                                                   int N, int K, int grow0)
{
  __shared__ short lds[2][128 * 64 + 192 * 64];  // 2 x (A[128][64] + B[192][64]) = 80 KiB
  const int tid  = threadIdx.x;
  const int lane = tid & 63;
  const int w    = tid >> 6;
  const int wm   = (w >> 1) * 64;
  const int wn   = (w & 1) * 96;
  const int m0   = blockIdx.y * 128;
  const int n0   = blockIdx.x * 192;
  const int lrow = lane >> 3;
  const int lseg = lane & 7;
  const int ksw  = (lseg * 8) ^ (lrow << 3);   // pre-swizzled source k (elements)

  f32x4 acc[4][6];
#pragma unroll
  for (int i = 0; i < 4; i++)
#pragma unroll
    for (int j = 0; j < 6; j++) acc[i][j] = (f32x4){0.f, 0.f, 0.f, 0.f};

  const int nk = K >> 6;

  auto issue = [&](int buf, int kt) {
    const int k0 = kt << 6;
    short* LA = &lds[buf][0];
    short* LB = &lds[buf][128 * 64];
#pragma unroll
    for (int i = 0; i < 4; i++) {
      const int chunk = w * 4 + i;
      gload_lds16(A + (size_t)(m0 + chunk * 8 + lrow) * K + (k0 + ksw), LA + chunk * 512);
    }
#pragma unroll
    for (int i = 0; i < 6; i++) {
      const int chunk = w * 6 + i;
      gload_lds16(Bt + (size_t)(n0 + chunk * 8 + lrow) * K + (k0 + ksw), LB + chunk * 512);
    }
  };

  issue(0, 0);
  __syncthreads();

  for (int kt = 0; kt < nk; kt++) {
    const int buf = kt & 1;
    if (kt + 1 < nk) issue(buf ^ 1, kt + 1);
    const char* LA = (const char*)&lds[buf][0];
    const char* LB = (const char*)&lds[buf][128 * 64];
#pragma unroll
    for (int kk = 0; kk < 2; kk++) {
      bf16x8 af[4], bg[6];
#pragma unroll
      for (int mf = 0; mf < 4; mf++) {
        const int row = wm + mf * 16 + (lane & 15);
        const int kb  = (kk * 64 + ((lane >> 4) << 4)) ^ ((row & 7) << 4);
        af[mf] = *(const bf16x8*)(LA + row * 128 + kb);
      }
#pragma unroll
      for (int nf = 0; nf < 6; nf++) {
        const int row = wn + nf * 16 + (lane & 15);
        const int kb  = (kk * 64 + ((lane >> 4) << 4)) ^ ((row & 7) << 4);
        bg[nf] = *(const bf16x8*)(LB + row * 128 + kb);
      }
#pragma unroll
      for (int mf = 0; mf < 4; mf++)
#pragma unroll
        for (int nf = 0; nf < 6; nf++)
          acc[mf][nf] = __builtin_amdgcn_mfma_f32_16x16x32_bf16(af[mf], bg[nf], acc[mf][nf], 0, 0, 0);
    }
    __syncthreads();
  }

  float bv[6];
  int ncol[6];
#pragma unroll
  for (int nf = 0; nf < 6; nf++) {
    ncol[nf] = n0 + wn + nf * 16 + (lane & 15);
    bv[nf]   = bias[ncol[nf]];
  }
#pragma unroll
  for (int mf = 0; mf < 4; mf++) {
#pragma unroll
    for (int r = 0; r < 4; r++) {
      const int m = m0 + wm + mf * 16 + ((lane >> 4) << 2) + r;
      if constexpr (MODE == 1) {
        const int gm  = grow0 + m;
        const int wid = gm / 49;
        const int nn  = gm - wid * 49;
        const int b_  = wid >> 6, wim = wid & 63;
        const int wy  = wim >> 3, wx = wim & 7;
        const int ny  = nn / 7, nx = nn - (nn / 7) * 7;
        int i = wy * 7 + ny + 3; if (i >= 56) i -= 56;
        int j = wx * 7 + nx + 3; if (j >= 56) j -= 56;
        const size_t t = (size_t)(b_ * 3136 + i * 56 + j) * 192;
        float* O = (float*)outv;
#pragma unroll
        for (int nf = 0; nf < 6; nf++)
          O[t + ncol[nf]] = acc[mf][nf][r] + bv[nf] + resid[t + ncol[nf]];
      } else {
        bf16* O = (bf16*)outv + (size_t)m * N;
#pragma unroll
        for (int nf = 0; nf < 6; nf++)
          O[ncol[nf]] = __float2bfloat16(acc[mf][nf][r] + bv[nf]);
      }
    }
  }
}

// ---------- fused MLP v2: LN2 + fc1 + GELU + fc2 + residual, one block = 64 rows ----------
// Weights in fragment-native transposed layout (w1t/w2t): every B-load is lane*16B
// coalesced. a0[64][192], a1[64][768] bf16 LDS, XOR-swizzled. 512 thr; LDS 120 KB.
// Phase1: wave w owns fc1 cols w*96 (acc[4][6]); Phase2: 2m x 4n (acc[2][3]).
__global__ __launch_bounds__(512) void mlp_kernel(const float* __restrict__ x,
                                                  const float* __restrict__ g2,
                                                  const float* __restrict__ b2,
                                                  const bf16* __restrict__ w1t,
                                                  const float* __restrict__ b1f,
                                                  const bf16* __restrict__ w2t,
                                                  const float* __restrict__ b2f,
                                                  float* __restrict__ out)
{
  __shared__ char a0[64 * 384];    // [64][192] bf16 swizzled, 24 KiB
  __shared__ char a1[64 * 1536];   // [64][768] bf16 swizzled, 96 KiB
  const int tid  = threadIdx.x;
  const int lane = tid & 63;
  const int w    = tid >> 6;
  const int m0   = blockIdx.x * 64;
  const int kq   = lane >> 4;          // k-quarter 0..3

  // ---- phase 0: LN2 on 64 rows (wave w -> rows w*8 .. w*8+7) ----
#pragma unroll
  for (int i = 0; i < 8; i++) {
    const int r = w * 8 + i;
    const float* xr = x + (size_t)(m0 + r) * 192;
    float v0 = xr[lane], v1 = xr[lane + 64], v2 = xr[lane + 128];
    float s = v0 + v1 + v2;
#pragma unroll
    for (int off = 32; off > 0; off >>= 1) s += __shfl_xor(s, off);
    const float mu = s * (1.0f / 192.0f);
    const float d0 = v0 - mu, d1 = v1 - mu, d2 = v2 - mu;
    float vs = d0 * d0 + d1 * d1 + d2 * d2;
#pragma unroll
    for (int off = 32; off > 0; off >>= 1) vs += __shfl_xor(vs, off);
    const float rstd = rsqrtf(vs * (1.0f / 192.0f) + 1e-5f);
    const int rx = (r & 7) << 4;
    *(unsigned short*)(a0 + r * 384 + ((2 * lane) ^ rx))         = f2bu(d0 * rstd * g2[lane]       + b2[lane]);
    *(unsigned short*)(a0 + r * 384 + ((2 * (lane + 64)) ^ rx))  = f2bu(d1 * rstd * g2[lane + 64]  + b2[lane + 64]);
    *(unsigned short*)(a0 + r * 384 + ((2 * (lane + 128)) ^ rx)) = f2bu(d2 * rstd * g2[lane + 128] + b2[lane + 128]);
  }
  __syncthreads();

  // ---- phase 1: a1 = gelu(a0 @ w1^T + b1); wave w -> cols w*96..w*96+95 ----
  {
    f32x4 acc1[4][6];
#pragma unroll
    for (int i = 0; i < 4; i++)
#pragma unroll
      for (int j = 0; j < 6; j++) acc1[i][j] = (f32x4){0.f, 0.f, 0.f, 0.f};
    for (int kk = 0; kk < 6; kk++) {
      bf16x8 af[4];
#pragma unroll
      for (int mf = 0; mf < 4; mf++) {
        const int ar = mf * 16 + (lane & 15);
        af[mf] = *(const bf16x8*)(a0 + ar * 384 + ((kk * 64 + (kq << 4)) ^ ((ar & 7) << 4)));
      }
#pragma unroll
      for (int nf = 0; nf < 6; nf++) {
        const int blk = (w * 6 + nf) * 6 + kk;         // nf_g*KT + kk, KT=6
        const bf16x8 bf_ = *(const bf16x8*)(w1t + (size_t)blk * 512 + lane * 8);
#pragma unroll
        for (int mf = 0; mf < 4; mf++)
          acc1[mf][nf] = __builtin_amdgcn_mfma_f32_16x16x32_bf16(af[mf], bf_, acc1[mf][nf], 0, 0, 0);
      }
    }
    float bv[6];
#pragma unroll
    for (int nf = 0; nf < 6; nf++) bv[nf] = b1f[w * 96 + nf * 16 + (lane & 15)];
#pragma unroll
    for (int mf = 0; mf < 4; mf++)
#pragma unroll
      for (int nf = 0; nf < 6; nf++)
#pragma unroll
        for (int r = 0; r < 4; r++) {
          const int row = mf * 16 + (kq << 2) + r;
          const int col = w * 96 + nf * 16 + (lane & 15);
          *(unsigned short*)(a1 + row * 1536 + ((2 * col) ^ ((row & 7) << 4)))
              = f2bu(gelu_f(acc1[mf][nf][r] + bv[nf]));
        }
  }
  __syncthreads();

  // ---- phase 2: out += a1 @ w2^T + b2; wave w -> m-half (w>>2), cols (w&3)*48 ----
  {
    const int mh  = (w >> 2) * 32;
    const int wn2 = (w & 3) * 48;
    f32x4 acc2[2][3];
#pragma unroll
    for (int i = 0; i < 2; i++)
#pragma unroll
      for (int j = 0; j < 3; j++) acc2[i][j] = (f32x4){0.f, 0.f, 0.f, 0.f};
    for (int kk = 0; kk < 24; kk++) {
      bf16x8 af[2];
#pragma unroll
      for (int mf = 0; mf < 2; mf++) {
        const int ar = mh + mf * 16 + (lane & 15);
        af[mf] = *(const bf16x8*)(a1 + ar * 1536 + ((kk * 64 + (kq << 4)) ^ ((ar & 7) << 4)));
      }
#pragma unroll
      for (int nf = 0; nf < 3; nf++) {
        const int blk = ((w & 3) * 3 + nf) * 24 + kk;  // nf_g*KT + kk, KT=24
        const bf16x8 bf_ = *(const bf16x8*)(w2t + (size_t)blk * 512 + lane * 8);
#pragma unroll
        for (int mf = 0; mf < 2; mf++)
          acc2[mf][nf] = __builtin_amdgcn_mfma_f32_16x16x32_bf16(af[mf], bf_, acc2[mf][nf], 0, 0, 0);
      }
    }
    float bv[3];
#pragma unroll
    for (int nf = 0; nf < 3; nf++) bv[nf] = b2f[wn2 + nf * 16 + (lane & 15)];
#pragma unroll
    for (int mf = 0; mf < 2; mf++)
#pragma unroll
      for (int nf = 0; nf < 3; nf++)
#pragma unroll
        for (int r = 0; r < 4; r++) {
          const int row = mh + mf * 16 + (kq << 2) + r;
          const size_t o = (size_t)(m0 + row) * 192 + wn2 + nf * 16 + (lane & 15);
          out[o] = acc2[mf][nf][r] + bv[nf] + out[o];
        }
  }
}

// ---------- MFMA windowed attention (unchanged from R7/R8) ----------
__global__ __launch_bounds__(64) void attn_kernel(const bf16* __restrict__ qkv,
                                                  const float* __restrict__ rpb,
                                                  bf16* __restrict__ aout)
{
  __shared__ unsigned short Vt[32 * 64];
  __shared__ unsigned short Pl[64 * 64];
  __shared__ float Bl[169];
  const int lane = threadIdx.x;
  const int wid  = blockIdx.x;
  const int h    = blockIdx.y;
  const unsigned short* qkvu = (const unsigned short*)qkv;
  const size_t base = (size_t)wid * 49 * 576 + h * 32;

#pragma unroll
  for (int i = 0; i < 3; i++) {
    const int idx = lane + 64 * i;
    if (idx < 169) Bl[idx] = rpb[idx * 6 + h];
  }
#pragma unroll
  for (int i = 0; i < 8; i++)
    ((unsigned long long*)Vt)[lane + 64 * i] = 0ull;

#pragma unroll
  for (int it = 0; it < 7; it++) {
    const int idx = lane + 64 * it;
    if (idx < 392) {
      const int n  = idx >> 3;
      const int d0 = (idx & 7) * 4;
      ushort4 v = *(const ushort4*)(qkvu + base + (size_t)n * 576 + 384 + d0);
      Vt[(d0 + 0) * 64 + (n ^ (((d0 + 0) & 7) << 3))] = v.x;
      Vt[(d0 + 1) * 64 + (n ^ (((d0 + 1) & 7) << 3))] = v.y;
      Vt[(d0 + 2) * 64 + (n ^ (((d0 + 2) & 7) << 3))] = v.z;
      Vt[(d0 + 3) * 64 + (n ^ (((d0 + 3) & 7) << 3))] = v.w;
    }
  }

  bf16x8 qf[4], kf[4];
#pragma unroll
  for (int t = 0; t < 4; t++) {
    int rq = (lane & 15) + t * 16; if (rq > 48) rq = 48;
    qf[t] = *(const bf16x8*)(qkvu + base + (size_t)rq * 576 + ((lane >> 4) * 8));
    kf[t] = *(const bf16x8*)(qkvu + base + (size_t)rq * 576 + 192 + ((lane >> 4) * 8));
  }

  f32x4 s[4][4];
#pragma unroll
  for (int mt = 0; mt < 4; mt++)
#pragma unroll
    for (int nt = 0; nt < 4; nt++)
      s[mt][nt] = __builtin_amdgcn_mfma_f32_16x16x32_bf16(qf[mt], kf[nt],
                    (f32x4){0.f, 0.f, 0.f, 0.f}, 0, 0, 0);

  const int wim = wid & 63;
  const int wy = wim >> 3, wx = wim & 7;
  int labn[4], ch[4], cw[4];
  bool cval[4];
#pragma unroll
  for (int nt = 0; nt < 4; nt++) {
    const int C = (lane & 15) + nt * 16;
    cval[nt] = (C < 49);
    const int cc = cval[nt] ? C : 48;
    ch[nt] = cc / 7; cw[nt] = cc - ch[nt] * 7;
    labn[nt] = reg3(wy * 7 + ch[nt]) * 3 + reg3(wx * 7 + cw[nt]);
  }

#pragma unroll
  for (int mt = 0; mt < 4; mt++) {
    f32x4 rm, sm, inv;
#pragma unroll
    for (int r = 0; r < 4; r++) {
      int R = mt * 16 + ((lane >> 4) << 2) + r; if (R > 48) R = 48;
      const int mh = R / 7, mw = R - (R / 7) * 7;
      const int labm = reg3(wy * 7 + mh) * 3 + reg3(wx * 7 + mw);
#pragma unroll
      for (int nt = 0; nt < 4; nt++) {
        float sv = s[mt][nt][r] * 0.1767766953f
                 + Bl[(mh - ch[nt] + 6) * 13 + (mw - cw[nt] + 6)];
        if (labn[nt] != labm) sv -= 100.f;
        if (!cval[nt]) sv = -3e38f;
        s[mt][nt][r] = sv;
      }
      rm[r] = fmaxf(fmaxf(s[mt][0][r], s[mt][1][r]), fmaxf(s[mt][2][r], s[mt][3][r]));
    }
#pragma unroll
    for (int mk = 1; mk < 16; mk <<= 1)
#pragma unroll
      for (int r = 0; r < 4; r++) rm[r] = fmaxf(rm[r], __shfl_xor(rm[r], mk));
#pragma unroll
    for (int r = 0; r < 4; r++) {
      float acc = 0.f;
#pragma unroll
      for (int nt = 0; nt < 4; nt++) {
        const float p = __expf(s[mt][nt][r] - rm[r]);
        s[mt][nt][r] = p;
        acc += p;
      }
      sm[r] = acc;
    }
#pragma unroll
    for (int mk = 1; mk < 16; mk <<= 1)
#pragma unroll
      for (int r = 0; r < 4; r++) sm[r] += __shfl_xor(sm[r], mk);
#pragma unroll
    for (int r = 0; r < 4; r++) inv[r] = 1.0f / sm[r];
#pragma unroll
    for (int nt = 0; nt < 4; nt++)
#pragma unroll
      for (int r = 0; r < 4; r++) {
        const int R = mt * 16 + ((lane >> 4) << 2) + r;
        const int C = (lane & 15) + nt * 16;
        Pl[R * 64 + (C ^ ((R & 7) << 3))] = f2bu(s[mt][nt][r] * inv[r]);
      }
  }

  f32x4 o[4][2];
#pragma unroll
  for (int mt = 0; mt < 4; mt++)
#pragma unroll
    for (int n2 = 0; n2 < 2; n2++) o[mt][n2] = (f32x4){0.f, 0.f, 0.f, 0.f};
#pragma unroll
  for (int kk = 0; kk < 2; kk++) {
    const int kb = kk * 64 + ((lane >> 4) << 4);
    bf16x8 vb[2];
#pragma unroll
    for (int n2 = 0; n2 < 2; n2++) {
      const int d = (lane & 15) + n2 * 16;
      vb[n2] = *(const bf16x8*)((const char*)Vt + d * 128 + (kb ^ ((d & 7) << 4)));
    }
#pragma unroll
    for (int mt = 0; mt < 4; mt++) {
      const int R = (lane & 15) + mt * 16;
      const bf16x8 pa = *(const bf16x8*)((const char*)Pl + R * 128 + (kb ^ ((R & 7) << 4)));
#pragma unroll
      for (int n2 = 0; n2 < 2; n2++)
        o[mt][n2] = __builtin_amdgcn_mfma_f32_16x16x32_bf16(pa, vb[n2], o[mt][n2], 0, 0, 0);
    }
  }

#pragma unroll
  for (int mt = 0; mt < 4; mt++)
#pragma unroll
    for (int r = 0; r < 4; r++) {
      const int R = mt * 16 + ((lane >> 4) << 2) + r;
      if (R < 49) {
        bf16* orow = aout + (size_t)(wid * 49 + R) * 192 + h * 32;
#pragma unroll
        for (int n2 = 0; n2 < 2; n2++)
          orow[n2 * 16 + (lane & 15)] = __float2bfloat16(o[mt][n2][r]);
      }
    }
}

extern "C" void kernel_launch(void* const* d_in, const int* in_sizes, int n_in,
                              void* d_out, int out_size, void* d_ws, size_t ws_size,
                              hipStream_t stream)
{
  (void)in_sizes; (void)n_in; (void)out_size;
  const float* x     = (const float*)d_in[0];
  const float* ln1g  = (const float*)d_in[1];
  const float* ln1b  = (const float*)d_in[2];
  const float* qkvw  = (const float*)d_in[3];
  const float* qkvb  = (const float*)d_in[4];
  const float* projw = (const float*)d_in[5];
  const float* projb = (const float*)d_in[6];
  const float* rpb   = (const float*)d_in[7];
  const float* ln2g  = (const float*)d_in[8];
  const float* ln2b  = (const float*)d_in[9];
  const float* fc1w  = (const float*)d_in[10];
  const float* fc1b  = (const float*)d_in[11];
  const float* fc2w  = (const float*)d_in[12];
  const float* fc2b  = (const float*)d_in[13];
  float* out = (float*)d_out;
  char* ws   = (char*)d_ws;

  // ---- bf16 weight copies at head of ws (884736 B total) ----
  bf16* wqkv = (bf16*)(ws);              // 110592 el, plain
  bf16* wproj = (bf16*)(ws + 221184);    //  36864 el, plain
  bf16* w1t  = (bf16*)(ws + 294912);     // 147456 el, fragment-transposed (K=192, KT=6)
  bf16* w2t  = (bf16*)(ws + 589824);     // 147456 el, fragment-transposed (K=768, KT=24)
  cvt_kernel<<<dim3(432), dim3(256), 0, stream>>>(qkvw, wqkv, 110592);
  cvt_kernel<<<dim3(144), dim3(256), 0, stream>>>(projw, wproj, 36864);
  cvtT_kernel<<<dim3(576), dim3(256), 0, stream>>>(fc1w, w1t, 192, 6, 147456);
  cvtT_kernel<<<dim3(576), dim3(256), 0, stream>>>(fc2w, w2t, 768, 24, 147456);

  char* cws = ws + 884736;
  const size_t avail = (ws_size > 884736ull) ? ws_size - 884736ull : 0;

  // ---- attention pipeline, chunked over batch (permutes are batch-local) ----
  int Bc = 32;
  while (Bc > 2 && (size_t)Bc * 4816896ull > avail) Bc >>= 1;
  const int nb = 32 / Bc;
  bf16* qkv_c  = (bf16*)cws;
  bf16* hwin_c = (bf16*)(cws + (size_t)Bc * 3612672ull);

  for (int c = 0; c < nb; c++) {
    const int R0 = c * Bc * 3136;       // global window-row offset
    const int Mc = Bc * 3136;
    ln_kernel<true><<<dim3(Mc / 4), dim3(256), 0, stream>>>(x, ln1g, ln1b, hwin_c, R0);
    gemm_kernel<0><<<dim3(3, Mc / 128), dim3(256), 0, stream>>>(hwin_c, wqkv, qkvb, nullptr, qkv_c, 576, 192, 0);
    attn_kernel<<<dim3(Bc * 64, 6), dim3(64), 0, stream>>>(qkv_c, rpb, hwin_c);
    gemm_kernel<1><<<dim3(1, Mc / 128), dim3(256), 0, stream>>>(hwin_c, wproj, projb, x, out, 192, 192, R0);
  }

  // ---- fused MLP v2: LN2 + fc1 + GELU + fc2 + residual (64 rows/block) ----
  mlp_kernel<<<dim3(1568), dim3(512), 0, stream>>>(out, ln2g, ln2b, w1t, fc1b, w2t, fc2b, out);
}